// Round 1
// 967.127 us; speedup vs baseline: 1.2318x; 1.2318x over previous
//
#include <hip/hip_runtime.h>

// MHA forward: B=2, S=2048, C=1024, H=16, D=64
// Round 3: fuse scores+PV (no unnormalized-E round trip through HBM).
//   attn_pv   : per (bh, q-tile) streams K/V, computes exp(QK^T*s), rowsum,
//               and O = E@V, with E repacked via LDS only.  Writes rowsum + O.
//   attn_write: recomputes QK^T (bitwise-identical), writes attn = E/rowsum ONCE (NT stores).
// E now makes 1 HBM trip (write) instead of 3 (write+read+write).
//
// d_out = [ out: 4096*1024 f32 | attn: 32*2048*2048 f32 ]
//   out region doubles as scratch: x-splits during projections, then O (split-bf16).
// d_ws  = [ QhHi QhLo KhHi KhLo VtHi VtLo : 6 x 4.19M bf16 | WtHi WtLo : 2 x 1M bf16 | rowsum: 65536 f32 ]
//   Qh slot is reused as fp32 tmp for the final projection output (Q dead by then).

#define S_  2048
#define C_  1024
#define H_  16
#define D_  64
#define BS_ 4096            // B*S
#define BH_ 32              // B*H

typedef unsigned short ushort_t;
typedef __attribute__((ext_vector_type(8))) short short8;
typedef __attribute__((ext_vector_type(4))) float floatx4;

#define GLDS16(gp, lp) __builtin_amdgcn_global_load_lds( \
    (__attribute__((address_space(1))) void*)(gp), \
    (__attribute__((address_space(3))) void*)(lp), 16, 0, 0)

#define MFMA16(a, b, c) __builtin_amdgcn_mfma_f32_16x16x32_bf16((a), (b), (c), 0, 0, 0)

__device__ __forceinline__ ushort_t f2bf(float x) {
  union { float f; unsigned u; } v; v.f = x;
  unsigned r = v.u + 0x7fffu + ((v.u >> 16) & 1u);   // round-to-nearest-even
  return (ushort_t)(r >> 16);
}
__device__ __forceinline__ float bf2f(ushort_t h) {
  union { unsigned u; float f; } v; v.u = ((unsigned)h) << 16; return v.f;
}

// ---------------------------------------------------------------------------
// split_plain: fp32[n4*4] -> hi/lo bf16 planes. One float4 per thread.
// ---------------------------------------------------------------------------
__global__ __launch_bounds__(256) void split_plain(
    const float* __restrict__ in, ushort_t* __restrict__ hi, ushort_t* __restrict__ lo)
{
  const int i = blockIdx.x * 256 + threadIdx.x;
  float4 v = ((const float4*)in)[i];
  ushort4 h, l;
  h.x = f2bf(v.x); l.x = f2bf(v.x - bf2f(h.x));
  h.y = f2bf(v.y); l.y = f2bf(v.y - bf2f(h.y));
  h.z = f2bf(v.z); l.z = f2bf(v.z - bf2f(h.z));
  h.w = f2bf(v.w); l.w = f2bf(v.w - bf2f(h.w));
  ((ushort4*)hi)[i] = h;
  ((ushort4*)lo)[i] = l;
}

// ---------------------------------------------------------------------------
// split_T: W[1024][1024] fp32 -> Wt hi/lo bf16 [n][k] (transposed).
// ---------------------------------------------------------------------------
__global__ __launch_bounds__(256) void split_T(
    const float* __restrict__ W, ushort_t* __restrict__ THi, ushort_t* __restrict__ TLo)
{
  __shared__ float t[64][65];
  const int k0 = blockIdx.x * 64, n0 = blockIdx.y * 64;
  const int tid = threadIdx.x;
  const int r = tid >> 4, c4 = (tid & 15) * 4;
#pragma unroll
  for (int p = 0; p < 4; ++p) {
    float4 v = *(const float4*)&W[(size_t)(k0 + p * 16 + r) * C_ + n0 + c4];
    t[p * 16 + r][c4 + 0] = v.x;
    t[p * 16 + r][c4 + 1] = v.y;
    t[p * 16 + r][c4 + 2] = v.z;
    t[p * 16 + r][c4 + 3] = v.w;
  }
  __syncthreads();
  const int n = tid >> 2, kc = (tid & 3) * 16;
#pragma unroll
  for (int j = 0; j < 16; ++j) {
    float x = t[kc + j][n];
    ushort_t h = f2bf(x);
    const size_t idx = (size_t)(n0 + n) * C_ + k0 + kc + j;
    THi[idx] = h;
    TLo[idx] = f2bf(x - bf2f(h));
  }
}

// ---------------------------------------------------------------------------
// gemm_proj: C[4096,1024] = A[4096,1024] @ Bt[1024,1024]^T + bias, split-bf16.
// ---------------------------------------------------------------------------
__global__ __launch_bounds__(256) void gemm_proj(
    const ushort_t* __restrict__ Ahi, const ushort_t* __restrict__ Alo,
    const ushort_t* __restrict__ Bhi, const ushort_t* __restrict__ Blo,
    const float* __restrict__ bias,
    ushort_t* __restrict__ OHi, ushort_t* __restrict__ OLo,
    float* __restrict__ OF, int mode)
{
  __shared__ ushort_t sA[2][128 * 32];
  __shared__ ushort_t sB[2][64 * 32];

  const int tid = threadIdx.x;
  const int wv = tid >> 6, ln = tid & 63;
  const int lq = ln >> 4, lr = ln & 15;
  const int wr = wv >> 1, wc = wv & 1;
  const int r0 = blockIdx.x * 128, c0 = blockIdx.y * 64;

  const int sar = wv * 32 + (ln >> 2);
  const int sbr = wv * 16 + (ln >> 2);
  const int skc = (ln & 3) * 8;

  floatx4 acc[4][2];
#pragma unroll
  for (int m = 0; m < 4; ++m)
#pragma unroll
    for (int n = 0; n < 2; ++n) acc[m][n] = (floatx4){0.f, 0.f, 0.f, 0.f};

  for (int kt = 0; kt < 1024; kt += 32) {
    __syncthreads();
#pragma unroll
    for (int c = 0; c < 2; ++c) {
      const int row = sar + c * 16;
      GLDS16(&Ahi[(size_t)(r0 + row) * 1024 + kt + skc], &sA[0][(wv * 32 + c * 16) * 32]);
      GLDS16(&Alo[(size_t)(r0 + row) * 1024 + kt + skc], &sA[1][(wv * 32 + c * 16) * 32]);
    }
    GLDS16(&Bhi[(size_t)(c0 + sbr) * 1024 + kt + skc], &sB[0][(wv * 16) * 32]);
    GLDS16(&Blo[(size_t)(c0 + sbr) * 1024 + kt + skc], &sB[1][(wv * 16) * 32]);
    __syncthreads();

    short8 af[4][2], bf[2][2];
#pragma unroll
    for (int t = 0; t < 4; ++t) {
      af[t][0] = *(const short8*)&sA[0][(wr * 64 + t * 16 + lr) * 32 + lq * 8];
      af[t][1] = *(const short8*)&sA[1][(wr * 64 + t * 16 + lr) * 32 + lq * 8];
    }
#pragma unroll
    for (int t = 0; t < 2; ++t) {
      bf[t][0] = *(const short8*)&sB[0][(wc * 32 + t * 16 + lr) * 32 + lq * 8];
      bf[t][1] = *(const short8*)&sB[1][(wc * 32 + t * 16 + lr) * 32 + lq * 8];
    }
#pragma unroll
    for (int m = 0; m < 4; ++m)
#pragma unroll
      for (int n = 0; n < 2; ++n) {
        acc[m][n] = MFMA16(af[m][1], bf[n][0], acc[m][n]);   // lo*hi
        acc[m][n] = MFMA16(af[m][0], bf[n][1], acc[m][n]);   // hi*lo
        acc[m][n] = MFMA16(af[m][0], bf[n][0], acc[m][n]);   // hi*hi
      }
  }

#pragma unroll
  for (int m = 0; m < 4; ++m) {
    const int grb = r0 + wr * 64 + m * 16 + lq * 4;
#pragma unroll
    for (int n = 0; n < 2; ++n) {
      const int gc = c0 + wc * 32 + n * 16 + lr;
      const float bs = bias[gc];
      if (mode == 2) {
#pragma unroll
        for (int r = 0; r < 4; ++r)
          OF[(size_t)(grb + r) * C_ + gc] = acc[m][n][r] + bs;
      } else if (mode == 0) {
        const int h = gc >> 6, d = gc & 63;
#pragma unroll
        for (int r = 0; r < 4; ++r) {
          const int gr = grb + r;
          const int b = gr >> 11, s = gr & (S_ - 1);
          const size_t idx = ((size_t)(b * H_ + h) * S_ + s) * D_ + d;
          float x = acc[m][n][r] + bs;
          ushort_t hx = f2bf(x);
          OHi[idx] = hx;
          OLo[idx] = f2bf(x - bf2f(hx));
        }
      } else {  // mode 1: Vt [bh][d][s]
        const int h = gc >> 6, d = gc & 63;
        const int b = grb >> 11, s = grb & (S_ - 1);
        const size_t idx = ((size_t)(b * H_ + h) * D_ + d) * S_ + s;
        ushort4 hv, lv;
        float x0 = acc[m][n][0] + bs, x1 = acc[m][n][1] + bs;
        float x2 = acc[m][n][2] + bs, x3 = acc[m][n][3] + bs;
        hv.x = f2bf(x0); lv.x = f2bf(x0 - bf2f(hv.x));
        hv.y = f2bf(x1); lv.y = f2bf(x1 - bf2f(hv.y));
        hv.z = f2bf(x2); lv.z = f2bf(x2 - bf2f(hv.z));
        hv.w = f2bf(x3); lv.w = f2bf(x3 - bf2f(hv.w));
        *(ushort4*)&OHi[idx] = hv;
        *(ushort4*)&OLo[idx] = lv;
      }
    }
  }
}

// ---------------------------------------------------------------------------
// attn_pv: per (bh, 128-row q-tile): stream j-tiles of 64:
//   S = Q@K^T (split-bf16), E = exp2(S*cexp), rowsum += E, O += E@V (E via LDS).
// Writes rowsum (full, no atomics) and O (split-bf16, merged-head layout).
// LDS: sQE (Q staging, then E tile) 32K + sK 16K + sV 16K = 64 KB -> 2 blocks/CU.
// ---------------------------------------------------------------------------
__global__ __launch_bounds__(256) void attn_pv(
    const ushort_t* __restrict__ QHi, const ushort_t* __restrict__ QLo,
    const ushort_t* __restrict__ KHi, const ushort_t* __restrict__ KLo,
    const ushort_t* __restrict__ VHi, const ushort_t* __restrict__ VLo,
    float* __restrict__ rowsum,
    ushort_t* __restrict__ OHi, ushort_t* __restrict__ OLo)
{
  __shared__ ushort_t sQE[2][2][128 * 32];   // [plane][kpanel] Q staging, then [plane][jpanel] E
  __shared__ ushort_t sK[2][2][64 * 32];     // [plane][kpanel][j-row*32+kc]
  __shared__ ushort_t sV[2][2][64 * 32];     // [plane][jpanel][d-row*32+jc]

  const int tid = threadIdx.x;
  const int wv = tid >> 6, ln = tid & 63;
  const int lq = ln >> 4, lr = ln & 15;
  const int wr = wv >> 1, wc = wv & 1;

  // bijective XCD swizzle over 512 blocks: each XCD owns 4 consecutive bh
  const int wgid = blockIdx.x;
  const int sw = (wgid & 7) * 64 + (wgid >> 3);
  const int bh = sw >> 4;
  const int i0 = (sw & 15) * 128;
  const int b = bh >> 4, h = bh & (H_ - 1);

  const ushort_t* Qh = QHi + (size_t)bh * S_ * D_;
  const ushort_t* Ql = QLo + (size_t)bh * S_ * D_;
  const ushort_t* Kh = KHi + (size_t)bh * S_ * D_;
  const ushort_t* Kl = KLo + (size_t)bh * S_ * D_;
  const ushort_t* Vh = VHi + (size_t)bh * D_ * S_;
  const ushort_t* Vl = VLo + (size_t)bh * D_ * S_;

  const int srow = ln >> 2;          // 0..15 staging row within 16-row chunk
  const int skc = (ln & 3) * 8;      // staging k offset (bf16 elems)

  // ---- stage Q (128x64, both planes), move to registers, then sQE is free ----
#pragma unroll
  for (int pl = 0; pl < 2; ++pl) {
    const ushort_t* src = pl ? Ql : Qh;
#pragma unroll
    for (int kp = 0; kp < 2; ++kp)
#pragma unroll
      for (int c = 0; c < 2; ++c)
        GLDS16(&src[(size_t)(i0 + wv * 32 + c * 16 + srow) * D_ + kp * 32 + skc],
               &sQE[pl][kp][(wv * 32 + c * 16) * 32]);
  }
  __syncthreads();
  short8 aq[4][2][2];                // [m][kpanel][plane]
#pragma unroll
  for (int m = 0; m < 4; ++m)
#pragma unroll
    for (int kp = 0; kp < 2; ++kp)
#pragma unroll
      for (int pl = 0; pl < 2; ++pl)
        aq[m][kp][pl] = *(const short8*)&sQE[pl][kp][(wr * 64 + m * 16 + lr) * 32 + lq * 8];

  const float cexp = 0.18033688011112042f;   // 0.125 * log2(e)
  floatx4 acc_o[4][2];
  float ps[4][4];
#pragma unroll
  for (int m = 0; m < 4; ++m) {
#pragma unroll
    for (int n = 0; n < 2; ++n) acc_o[m][n] = (floatx4){0.f, 0.f, 0.f, 0.f};
#pragma unroll
    for (int r = 0; r < 4; ++r) ps[m][r] = 0.f;
  }

  for (int jt = 0; jt < 32; ++jt) {
    const int j0 = jt * 64;
    __syncthreads();    // prev PV reads of sQE/sV done; aq reads done (jt==0)
#pragma unroll
    for (int pl = 0; pl < 2; ++pl) {
      const ushort_t* ks = pl ? Kl : Kh;
      const ushort_t* vs = pl ? Vl : Vh;
#pragma unroll
      for (int kp = 0; kp < 2; ++kp)
        GLDS16(&ks[(size_t)(j0 + wv * 16 + srow) * D_ + kp * 32 + skc],
               &sK[pl][kp][(wv * 16) * 32]);
#pragma unroll
      for (int jp = 0; jp < 2; ++jp)
        GLDS16(&vs[(size_t)(wv * 16 + srow) * S_ + j0 + jp * 32 + skc],
               &sV[pl][jp][(wv * 16) * 32]);
    }
    __syncthreads();

    // ---- QK^T: 128x64 tile, wave quadrant 64(q) x 32(j) ----
    floatx4 acc_s[4][2];
#pragma unroll
    for (int m = 0; m < 4; ++m)
#pragma unroll
      for (int n = 0; n < 2; ++n) acc_s[m][n] = (floatx4){0.f, 0.f, 0.f, 0.f};
#pragma unroll
    for (int kp = 0; kp < 2; ++kp) {
      short8 bk[2][2];
#pragma unroll
      for (int n = 0; n < 2; ++n)
#pragma unroll
        for (int pl = 0; pl < 2; ++pl)
          bk[n][pl] = *(const short8*)&sK[pl][kp][(wc * 32 + n * 16 + lr) * 32 + lq * 8];
#pragma unroll
      for (int m = 0; m < 4; ++m)
#pragma unroll
        for (int n = 0; n < 2; ++n) {
          acc_s[m][n] = MFMA16(aq[m][kp][1], bk[n][0], acc_s[m][n]);
          acc_s[m][n] = MFMA16(aq[m][kp][0], bk[n][1], acc_s[m][n]);
          acc_s[m][n] = MFMA16(aq[m][kp][0], bk[n][0], acc_s[m][n]);
        }
    }

    // ---- exp, rowsum partials, E -> LDS split-bf16 (D-layout -> A-frag layout) ----
#pragma unroll
    for (int m = 0; m < 4; ++m)
#pragma unroll
      for (int n = 0; n < 2; ++n)
#pragma unroll
        for (int r = 0; r < 4; ++r) {
          float e = exp2f(acc_s[m][n][r] * cexp);
          ps[m][r] += e;
          ushort_t eh = f2bf(e);
          ushort_t el = f2bf(e - bf2f(eh));
          const int row = wr * 64 + m * 16 + lq * 4 + r;
          sQE[0][wc][row * 32 + n * 16 + lr] = eh;
          sQE[1][wc][row * 32 + n * 16 + lr] = el;
        }
    __syncthreads();

    // ---- PV: O[128x64] += E[128x64] @ V[64x64], wave quadrant 64(q) x 32(d) ----
#pragma unroll
    for (int kp = 0; kp < 2; ++kp) {
      short8 ae[4][2], bv[2][2];
#pragma unroll
      for (int m = 0; m < 4; ++m)
#pragma unroll
        for (int pl = 0; pl < 2; ++pl)
          ae[m][pl] = *(const short8*)&sQE[pl][kp][(wr * 64 + m * 16 + lr) * 32 + lq * 8];
#pragma unroll
      for (int n = 0; n < 2; ++n)
#pragma unroll
        for (int pl = 0; pl < 2; ++pl)
          bv[n][pl] = *(const short8*)&sV[pl][kp][(wc * 32 + n * 16 + lr) * 32 + lq * 8];
#pragma unroll
      for (int m = 0; m < 4; ++m)
#pragma unroll
        for (int n = 0; n < 2; ++n) {
          acc_o[m][n] = MFMA16(ae[m][1], bv[n][0], acc_o[m][n]);
          acc_o[m][n] = MFMA16(ae[m][0], bv[n][1], acc_o[m][n]);
          acc_o[m][n] = MFMA16(ae[m][0], bv[n][0], acc_o[m][n]);
        }
    }
  }

  // ---- rowsum reduce (LDS, no atomics) + O write ----
  __syncthreads();
  float* sRsp = (float*)&sV[0][0][0];   // [2][128] per-wave-column partials
  float* sTot = sRsp + 256;             // [128] totals
#pragma unroll
  for (int m = 0; m < 4; ++m)
#pragma unroll
    for (int r = 0; r < 4; ++r) {
      float s = ps[m][r];
      s += __shfl_xor(s, 1);
      s += __shfl_xor(s, 2);
      s += __shfl_xor(s, 4);
      s += __shfl_xor(s, 8);
      if (lr == 0) sRsp[wc * 128 + wr * 64 + m * 16 + lq * 4 + r] = s;
    }
  __syncthreads();
  if (tid < 128) {
    float t = sRsp[tid] + sRsp[128 + tid];
    sTot[tid] = t;
    rowsum[bh * S_ + i0 + tid] = t;
  }
  __syncthreads();

#pragma unroll
  for (int m = 0; m < 4; ++m) {
    const int rows = wr * 64 + m * 16 + lq * 4;
#pragma unroll
    for (int r = 0; r < 4; ++r) {
      const float rv = 1.0f / sTot[rows + r];
      const size_t orow = (size_t)(b * S_ + i0 + rows + r) * C_ + h * D_;
#pragma unroll
      for (int n = 0; n < 2; ++n) {
        const int d = wc * 32 + n * 16 + lr;
        float x = acc_o[m][n][r] * rv;
        ushort_t hx = f2bf(x);
        OHi[orow + d] = hx;
        OLo[orow + d] = f2bf(x - bf2f(hx));
      }
    }
  }
}

// ---------------------------------------------------------------------------
// attn_write: recompute QK^T tile (identical MFMA sequence to attn_pv ->
// bitwise-identical exp), scale by 1/rowsum, write normalized attn ONCE (NT).
// ---------------------------------------------------------------------------
__global__ __launch_bounds__(256) void attn_write(
    const ushort_t* __restrict__ QHi, const ushort_t* __restrict__ QLo,
    const ushort_t* __restrict__ KHi, const ushort_t* __restrict__ KLo,
    const float* __restrict__ rowsum, float* __restrict__ attn)
{
  __shared__ ushort_t sA[2][128 * 32];
  __shared__ ushort_t sB[2][128 * 32];

  const int tid = threadIdx.x;
  const int wv = tid >> 6, ln = tid & 63;
  const int lq = ln >> 4, lr = ln & 15;
  const int wr = wv >> 1, wc = wv & 1;

  // bijective XCD swizzle over 8192 blocks: each XCD owns 4 consecutive bh
  const int wgid = blockIdx.x;
  const int sw = (wgid & 7) * 1024 + (wgid >> 3);
  const int bh = sw >> 8;
  const int t8 = sw & 255;
  const int i0 = (t8 >> 4) * 128, j0 = (t8 & 15) * 128;

  const ushort_t* Qh = QHi + (size_t)bh * S_ * D_;
  const ushort_t* Ql = QLo + (size_t)bh * S_ * D_;
  const ushort_t* Kh = KHi + (size_t)bh * S_ * D_;
  const ushort_t* Kl = KLo + (size_t)bh * S_ * D_;

  const int sar = wv * 32 + (ln >> 2);
  const int skc = (ln & 3) * 8;

  floatx4 acc[4][4];
#pragma unroll
  for (int m = 0; m < 4; ++m)
#pragma unroll
    for (int n = 0; n < 4; ++n) acc[m][n] = (floatx4){0.f, 0.f, 0.f, 0.f};

#pragma unroll
  for (int kt = 0; kt < 64; kt += 32) {
    __syncthreads();
#pragma unroll
    for (int c = 0; c < 2; ++c) {
      const int row = sar + c * 16;
      GLDS16(&Qh[(size_t)(i0 + row) * D_ + kt + skc], &sA[0][(wv * 32 + c * 16) * 32]);
      GLDS16(&Ql[(size_t)(i0 + row) * D_ + kt + skc], &sA[1][(wv * 32 + c * 16) * 32]);
      GLDS16(&Kh[(size_t)(j0 + row) * D_ + kt + skc], &sB[0][(wv * 32 + c * 16) * 32]);
      GLDS16(&Kl[(size_t)(j0 + row) * D_ + kt + skc], &sB[1][(wv * 32 + c * 16) * 32]);
    }
    __syncthreads();

    short8 af[4][2], bf[4][2];
#pragma unroll
    for (int t = 0; t < 4; ++t) {
      af[t][0] = *(const short8*)&sA[0][(wr * 64 + t * 16 + lr) * 32 + lq * 8];
      af[t][1] = *(const short8*)&sA[1][(wr * 64 + t * 16 + lr) * 32 + lq * 8];
      bf[t][0] = *(const short8*)&sB[0][(wc * 64 + t * 16 + lr) * 32 + lq * 8];
      bf[t][1] = *(const short8*)&sB[1][(wc * 64 + t * 16 + lr) * 32 + lq * 8];
    }
#pragma unroll
    for (int m = 0; m < 4; ++m)
#pragma unroll
      for (int n = 0; n < 4; ++n) {
        acc[m][n] = MFMA16(af[m][1], bf[n][0], acc[m][n]);
        acc[m][n] = MFMA16(af[m][0], bf[n][1], acc[m][n]);
        acc[m][n] = MFMA16(af[m][0], bf[n][0], acc[m][n]);
      }
  }

  float* Eb = attn + (size_t)bh * S_ * S_;
  const float cexp = 0.18033688011112042f;
#pragma unroll
  for (int m = 0; m < 4; ++m) {
    const int grb = i0 + wr * 64 + m * 16 + lq * 4;
    float rv[4];
#pragma unroll
    for (int r = 0; r < 4; ++r) rv[r] = 1.0f / rowsum[bh * S_ + grb + r];
#pragma unroll
    for (int n = 0; n < 4; ++n) {
      const int gc = j0 + wc * 64 + n * 16 + lr;
#pragma unroll
      for (int r = 0; r < 4; ++r) {
        float e = exp2f(acc[m][n][r] * cexp) * rv[r];
        __builtin_nontemporal_store(e, &Eb[(size_t)(grb + r) * S_ + gc]);
      }
    }
  }
}

// ---------------------------------------------------------------------------
// copy4: fp32 block copy (tmp out -> real out region).
// ---------------------------------------------------------------------------
__global__ __launch_bounds__(256) void copy4(
    const float* __restrict__ in, float* __restrict__ out)
{
  const int i = blockIdx.x * 256 + threadIdx.x;
  ((float4*)out)[i] = ((const float4*)in)[i];
}

// ---------------------------------------------------------------------------
extern "C" void kernel_launch(void* const* d_in, const int* in_sizes, int n_in,
                              void* d_out, int out_size, void* d_ws, size_t ws_size,
                              hipStream_t stream)
{
  (void)in_sizes; (void)n_in; (void)out_size; (void)ws_size;

  const float* q  = (const float*)d_in[0];
  const float* k  = (const float*)d_in[1];
  const float* v  = (const float*)d_in[2];
  const float* wq = (const float*)d_in[3];
  const float* bq = (const float*)d_in[4];
  const float* wk = (const float*)d_in[5];
  const float* bk = (const float*)d_in[6];
  const float* wv = (const float*)d_in[7];
  const float* bv = (const float*)d_in[8];
  const float* wo = (const float*)d_in[9];
  const float* bo = (const float*)d_in[10];

  const size_t NE = (size_t)BS_ * C_;          // 4,194,304

  float* outF = (float*)d_out;
  float* Ebuf = outF + NE;                      // attn region
  ushort_t* XSHi = (ushort_t*)d_out;            // out region scratch: x-splits, then O
  ushort_t* XSLo = XSHi + NE;

  ushort_t* ws16 = (ushort_t*)d_ws;
  ushort_t* QhHi = ws16;           ushort_t* QhLo = QhHi + NE;
  ushort_t* KhHi = QhLo + NE;      ushort_t* KhLo = KhHi + NE;
  ushort_t* VtHi = KhLo + NE;      ushort_t* VtLo = VtHi + NE;
  ushort_t* WtHi = VtLo + NE;      ushort_t* WtLo = WtHi + (size_t)C_ * C_;
  float* rowsum = (float*)(WtLo + (size_t)C_ * C_);

  const dim3 gS(NE / 4 / 256);          // split_plain grid
  const dim3 gT(16, 16);                // split_T grid
  const dim3 gP(BS_ / 128, C_ / 64);    // proj grid (32,16)

  // Q projection
  split_T<<<gT, 256, 0, stream>>>(wq, WtHi, WtLo);
  split_plain<<<gS, 256, 0, stream>>>(q, XSHi, XSLo);
  gemm_proj<<<gP, 256, 0, stream>>>(XSHi, XSLo, WtHi, WtLo, bq, QhHi, QhLo, nullptr, 0);
  // K projection
  split_T<<<gT, 256, 0, stream>>>(wk, WtHi, WtLo);
  split_plain<<<gS, 256, 0, stream>>>(k, XSHi, XSLo);
  gemm_proj<<<gP, 256, 0, stream>>>(XSHi, XSLo, WtHi, WtLo, bk, KhHi, KhLo, nullptr, 0);
  // V projection (transposed output)
  split_T<<<gT, 256, 0, stream>>>(wv, WtHi, WtLo);
  split_plain<<<gS, 256, 0, stream>>>(v, XSHi, XSLo);
  gemm_proj<<<gP, 256, 0, stream>>>(XSHi, XSLo, WtHi, WtLo, bv, VtHi, VtLo, nullptr, 1);

  // fused attention: rowsum + O (O -> out-region scratch; Q/K/V stay intact)
  attn_pv<<<dim3(512), 256, 0, stream>>>(QhHi, QhLo, KhHi, KhLo, VtHi, VtLo,
                                         rowsum, XSHi, XSLo);
  // normalized attn, written exactly once
  attn_write<<<dim3(8192), 256, 0, stream>>>(QhHi, QhLo, KhHi, KhLo, rowsum, Ebuf);

  // output projection: O (out-region) @ Wo -> tmp fp32 in ws (Qh slot is dead), then copy
  split_T<<<gT, 256, 0, stream>>>(wo, WtHi, WtLo);
  float* tmpF = (float*)QhHi;
  gemm_proj<<<gP, 256, 0, stream>>>(XSHi, XSLo, WtHi, WtLo, bo, nullptr, nullptr, tmpF, 2);
  copy4<<<dim3(NE / 4 / 256), 256, 0, stream>>>(tmpF, outF);
}